// Round 6
// baseline (188.938 us; speedup 1.0000x reference)
//
#include <hip/hip_runtime.h>
#include <math.h>

#define Bsz 512
#define INsz 128
#define Nn 256
#define Ww 64
#define Rr 4
#define Uu 256
#define OUTsz 128
#define IFACEsz 471
#define XDIM 384   /* IN + W*R */
#define KL 640     /* XDIM + U */
#define G4 1024    /* 4*U */

__device__ __forceinline__ float sigf(float x){ return 1.0f/(1.0f+expf(-x)); }
__device__ __forceinline__ float softplusf_(float x){ return fmaxf(x,0.0f) + log1pf(expf(-fabsf(x))); }
__device__ __forceinline__ float4 f4fma(float s, float4 a, float4 acc){
  acc.x += s*a.x; acc.y += s*a.y; acc.z += s*a.z; acc.w += s*a.w; return acc;
}
__device__ __forceinline__ float4 f4add(float4 a, float4 b){
  a.x+=b.x; a.y+=b.y; a.z+=b.z; a.w+=b.w; return a;
}
__device__ __forceinline__ float4 f4max(float4 a, float4 b){
  a.x=fmaxf(a.x,b.x); a.y=fmaxf(a.y,b.y); a.z=fmaxf(a.z,b.z); a.w=fmaxf(a.w,b.w); return a;
}

// ---------------- K0: pad Wi to 512 cols -----------------------------------
__global__ __launch_bounds__(256) void k_packWi(
  const float* __restrict__ Wi, float* __restrict__ Wip)
{
  const int k = blockIdx.x, t = threadIdx.x;
  const int j2 = t + 256;
  Wip[(size_t)k*512 + t]  = Wi[(size_t)k*IFACEsz + t];
  Wip[(size_t)k*512 + j2] = (j2 < IFACEsz) ? Wi[(size_t)k*IFACEsz + j2] : 0.0f;
}

// ---------------- K1: LSTM GEMM + epilogue fused (inline X concat) ---------
__global__ __launch_bounds__(512) void k_lstm(
  const float* __restrict__ inputs, const float* __restrict__ rvp,
  const float* __restrict__ hp, const float* __restrict__ Wk,
  const float* __restrict__ Wr, const float* __restrict__ bl,
  const float* __restrict__ cprev, float* __restrict__ h_out)
{
  const int t = threadIdx.x;
  const int tx = t & 7;
  const int tg = (t >> 3) & 3;
  const int tb = t >> 5;
  const int b0 = blockIdx.x * 16;
  const int cg = blockIdx.y * 32;
  const int col = tg*256 + cg + tx*4;
  __shared__ float Xs[16][68];
  __shared__ float zs[16][4][36];
  float4 acc = {0,0,0,0};
  for (int kc = 0; kc < KL; kc += 64){
    if (t < 256){
      const int rr = t >> 4, cc = (t & 15)*4;
      const int c = kc + cc;
      const float* src;
      if (c < INsz)      src = inputs + (size_t)(b0+rr)*INsz + c;
      else if (c < XDIM) src = rvp + (size_t)(b0+rr)*(Ww*Rr) + (c - INsz);
      else               src = hp + (size_t)(b0+rr)*Uu + (c - XDIM);
      *reinterpret_cast<float4*>(&Xs[rr][cc]) = *reinterpret_cast<const float4*>(src);
    }
    __syncthreads();
    const float* Wp = ((kc < XDIM) ? (Wk + (size_t)kc*G4) : (Wr + (size_t)(kc-XDIM)*G4)) + col;
    #pragma unroll 8
    for (int kk=0; kk<64; ++kk){
      float4 w4 = *reinterpret_cast<const float4*>(Wp + (size_t)kk*G4);
      acc = f4fma(Xs[tb][kk], w4, acc);
    }
    __syncthreads();
  }
  {
    float4 b4 = *reinterpret_cast<const float4*>(bl + col);
    acc = f4add(acc, b4);
  }
  *reinterpret_cast<float4*>(&zs[tb][tg][tx*4]) = acc;
  __syncthreads();
  {
    const int b = t >> 5, c = t & 31;
    float zi = zs[b][0][c], zf = zs[b][1][c], zc_ = zs[b][2][c], zo = zs[b][3][c];
    float cc = sigf(zf)*cprev[(size_t)(b0+b)*Uu + cg + c] + sigf(zi)*tanhf(zc_);
    float h = sigf(zo)*tanhf(cc);
    h = fminf(fmaxf(h,-20.0f),20.0f);
    h_out[(size_t)(b0+b)*Uu + cg + c] = h;
  }
}

// ---------------- K2a: interface GEMM v = h * Wip --------------------------
__global__ __launch_bounds__(256) void k_ifgemm(
  const float* __restrict__ h_ws, const float* __restrict__ Wip, float* __restrict__ v_ws)
{
  const int t = threadIdx.x;
  const int tx = t & 15, ty = t >> 4;
  const int b0 = blockIdx.x*16;
  const int col = blockIdx.y*64 + tx*4;
  __shared__ float Hs[16][68];
  float4 acc = {0,0,0,0};
  for (int kc = 0; kc < Uu; kc += 64){
    {
      int rr = t >> 4, cc = (t & 15)*4;
      *reinterpret_cast<float4*>(&Hs[rr][cc]) =
        *reinterpret_cast<const float4*>(h_ws + (size_t)(b0+rr)*Uu + kc + cc);
    }
    __syncthreads();
    const float* Wp = Wip + (size_t)kc*512 + col;
    #pragma unroll 8
    for (int kk=0; kk<64; ++kk){
      float4 w4 = *reinterpret_cast<const float4*>(Wp + (size_t)kk*512);
      acc = f4fma(Hs[ty][kk], w4, acc);
    }
    __syncthreads();
  }
  *reinterpret_cast<float4*>(v_ws + (size_t)(b0+ty)*512 + col) = acc;
}

// ---------------- K2b: interface logic -------------------------------------
__global__ __launch_bounds__(256) void k_iface2(
  const float* __restrict__ v_ws, const float* __restrict__ bi,
  const float* __restrict__ usage, const float* __restrict__ wwp,
  const float* __restrict__ wrp, const float* __restrict__ prec,
  const float* __restrict__ M,
  float* __restrict__ ww_ws, float* __restrict__ er_ws, float* __restrict__ wv_ws,
  float* __restrict__ rk_ws, float* __restrict__ krn_ws, float* __restrict__ rstr_ws,
  float* __restrict__ rm_ws, float* __restrict__ P_ws, float* __restrict__ Q_ws)
{
  const int b = blockIdx.x, t = threadIdx.x;
  __shared__ float vl[IFACEsz];
  __shared__ float wkey[Ww];
  __shared__ float ul[Nn], sul[Nn], cpl[Nn], red[Nn];
  __shared__ __align__(16) float4 red4[Nn];
  __shared__ float scal[8];
  for (int j=t; j<IFACEsz; j+=256) vl[j] = v_ws[(size_t)b*512 + j] + bi[j];
  __syncthreads();
  if (t < Ww){
    wkey[t] = vl[260+t];
    er_ws[b*Ww+t] = sigf(vl[325+t]);
    wv_ws[b*Ww+t] = vl[389+t];
  }
  rk_ws[b*Ww*Rr + t] = vl[t];
  if (t < Rr){
    rstr_ws[b*Rr+t] = 1.0f + softplusf_(vl[256+t]);
    float ssum = 0.0f;
    for (int w=0;w<Ww;++w){ float v = vl[w*Rr+t]; ssum += v*v; }
    krn_ws[b*Rr+t] = sqrtf(ssum);
    float q0=vl[459+t], q1=vl[463+t], q2=vl[467+t];
    float mm = fmaxf(q0, fmaxf(q1,q2));
    float e0=expf(q0-mm), e1=expf(q1-mm), e2=expf(q2-mm);
    float inv = 1.0f/(e0+e1+e2);
    rm_ws[b*12 + t]     = e0*inv;
    rm_ws[b*12 + 4 + t] = e1*inv;
    rm_ws[b*12 + 8 + t] = e2*inv;
    scal[4+t] = sigf(vl[453+t]);
  }
  if (t == 0){
    scal[0] = 1.0f + softplusf_(vl[324]);
    scal[1] = sigf(vl[457]);
    scal[2] = sigf(vl[458]);
    float ssum=0.0f;
    for (int w=0;w<Ww;++w){ float v=vl[260+w]; ssum += v*v; }
    scal[3] = sqrtf(ssum);
  }
  __syncthreads();
  float4 wr4 = *reinterpret_cast<const float4*>(wrp + ((size_t)b*Nn + t)*Rr);
  float psi = (1.0f - scal[4]*wr4.x)*(1.0f - scal[5]*wr4.y)
            * (1.0f - scal[6]*wr4.z)*(1.0f - scal[7]*wr4.w);
  float us = usage[b*Nn+t], wp = wwp[b*Nn+t];
  float u = (us + wp - us*wp)*psi;
  ul[t] = u;
  __syncthreads();
  int rank = 0;
  for (int m=0;m<Nn;++m){
    float um = ul[m];
    rank += (um < u || (um == u && m < t)) ? 1 : 0;
  }
  sul[rank] = u;
  __syncthreads();
  cpl[t] = sul[t];
  __syncthreads();
  for (int d=1; d<Nn; d<<=1){
    float a = cpl[t];
    float m_ = (t >= d) ? cpl[t-d] : 1.0f;
    __syncthreads();
    cpl[t] = a*m_;
    __syncthreads();
  }
  float cpexcl = (rank == 0) ? 1.0f : cpl[rank-1];
  float alloc = (1.0f - u)*cpexcl;
  const float* Mrow = M + ((size_t)b*Nn + t)*Ww;
  float dot=0.0f, nrm=0.0f;
  #pragma unroll 4
  for (int w=0;w<Ww;w+=4){
    float4 m4 = *reinterpret_cast<const float4*>(Mrow + w);
    dot += m4.x*wkey[w] + m4.y*wkey[w+1] + m4.z*wkey[w+2] + m4.w*wkey[w+3];
    nrm += m4.x*m4.x + m4.y*m4.y + m4.z*m4.z + m4.w*m4.w;
  }
  float sim = dot/(sqrtf(nrm)*scal[3] + 1e-6f);
  float sc = scal[0]*sim;
  red[t] = sc; __syncthreads();
  for (int st=128; st>0; st>>=1){ if (t<st) red[t] = fmaxf(red[t], red[t+st]); __syncthreads(); }
  float mx = red[0]; __syncthreads();
  float e = expf(sc - mx);
  red[t] = e; __syncthreads();
  for (int st=128; st>0; st>>=1){ if (t<st) red[t] += red[t+st]; __syncthreads(); }
  float cw = e/red[0];
  float ww = scal[2]*(scal[1]*alloc + (1.0f - scal[1])*cw);
  ww_ws[b*Nn+t] = ww;
  __syncthreads();
  float pr = prec[b*Nn+t];
  float4 pv; pv.x = pr*wr4.x; pv.y = pr*wr4.y; pv.z = pr*wr4.z; pv.w = pr*wr4.w;
  red4[t] = pv; __syncthreads();
  for (int st=128; st>0; st>>=1){ if (t<st) red4[t] = f4add(red4[t], red4[t+st]); __syncthreads(); }
  if (t==0) *reinterpret_cast<float4*>(P_ws + b*Rr) = red4[0];
  __syncthreads();
  float4 qv; qv.x = ww*wr4.x; qv.y = ww*wr4.y; qv.z = ww*wr4.z; qv.w = ww*wr4.w;
  red4[t] = qv; __syncthreads();
  for (int st=128; st>0; st>>=1){ if (t<st) red4[t] = f4add(red4[t], red4[t+st]); __syncthreads(); }
  if (t==0) *reinterpret_cast<float4*>(Q_ws + b*Rr) = red4[0];
}

// ---------------- K3: link products v4 -------------------------------------
// grid (B, 4): strip of 64 rows.
// Phase A: col partials with float4 loads (wave reads a full 1KB row/iter),
//          per-row-group partials reduced through a 16KB LDS buffer.
// Phase B: row products re-reading the L2-hot strip, seg-padded LDS mirrors
//          of wr/ww to kill bank conflicts.
__global__ __launch_bounds__(256) void k_link(
  const float* __restrict__ link, const float* __restrict__ wrp,
  const float* __restrict__ ww_ws,
  float* __restrict__ rowA, float* __restrict__ rowC,
  float* __restrict__ colAp, float* __restrict__ colCp, float* __restrict__ diag)
{
  const int b = blockIdx.x, s = blockIdx.y, t = threadIdx.x;
  const int n0 = s*64;
  __shared__ __align__(16) float4 wrl4[Nn];      // AoS by n (phase A broadcast)
  __shared__ __align__(16) float4 wrl4p[4][66];  // seg-padded (phase B)
  __shared__ float wws[Nn];
  __shared__ float wwsp[4][68];
  __shared__ __align__(16) float4 cred[4][Nn];   // 16KB reduce buffer
  {
    float4 w4 = *reinterpret_cast<const float4*>(wrp + ((size_t)b*Nn + t)*Rr);
    wrl4[t] = w4;
    wrl4p[t>>6][t&63] = w4;
    float w = ww_ws[(size_t)b*Nn + t];
    wws[t] = w;
    wwsp[t>>6][t&63] = w;
  }
  __syncthreads();
  const float* Lb = link + (size_t)b*Nn*Nn;
  // ---- Phase A: thread (cq = t&63, g = t>>6) covers cols 4cq..4cq+3,
  //      rows n0+g*16 .. n0+g*16+15. Wave = one full row per iteration.
  const int cq = t & 63, g = t >> 6;
  const int c4 = cq*4;
  {
    float4 z = {0,0,0,0};
    float4 a0=z,a1=z,a2=z,a3=z, q0=z,q1=z,q2=z,q3=z;
    #pragma unroll
    for (int i=0;i<16;++i){
      const int n = n0 + g*16 + i;
      float4 l4 = *reinterpret_cast<const float4*>(Lb + (size_t)n*Nn + c4);
      float4 wn = wrl4[n];
      float wwn = wws[n];
      a0 = f4fma(l4.x, wn, a0); a1 = f4fma(l4.y, wn, a1);
      a2 = f4fma(l4.z, wn, a2); a3 = f4fma(l4.w, wn, a3);
      q0 = f4fma(l4.x*wwn, wn, q0); q1 = f4fma(l4.y*wwn, wn, q1);
      q2 = f4fma(l4.z*wwn, wn, q2); q3 = f4fma(l4.w*wwn, wn, q3);
      if ((n>>2) == cq){
        const int r = n&3;
        float c = (r==0) ? l4.x : (r==1) ? l4.y : (r==2) ? l4.z : l4.w;
        diag[(size_t)b*Nn + n] = c;
      }
    }
    cred[g][c4+0]=a0; cred[g][c4+1]=a1; cred[g][c4+2]=a2; cred[g][c4+3]=a3;
    __syncthreads();
    {
      float4 sA = f4add(f4add(cred[0][t],cred[1][t]),f4add(cred[2][t],cred[3][t]));
      *reinterpret_cast<float4*>(colAp + (((size_t)s*Bsz + b)*Nn + t)*Rr) = sA;
    }
    __syncthreads();
    cred[g][c4+0]=q0; cred[g][c4+1]=q1; cred[g][c4+2]=q2; cred[g][c4+3]=q3;
    __syncthreads();
    {
      float4 sC = f4add(f4add(cred[0][t],cred[1][t]),f4add(cred[2][t],cred[3][t]));
      *reinterpret_cast<float4*>(colCp + (((size_t)s*Bsz + b)*Nn + t)*Rr) = sC;
    }
  }
  // ---- Phase B: row products; 4 threads/row, seg = 64-col chunk (L2-hot)
  {
    const int row = n0 + (t >> 2), seg = t & 3;
    const float* Lr = Lb + (size_t)row*Nn + seg*64;
    float ra0=0,ra1=0,ra2=0,ra3=0, rc0=0,rc1=0,rc2=0,rc3=0;
    #pragma unroll
    for (int k=0;k<16;++k){
      float4 l4 = *reinterpret_cast<const float4*>(Lr + k*4);
      float4 ww4 = *reinterpret_cast<const float4*>(&wwsp[seg][k*4]);
      float4 w0 = wrl4p[seg][k*4], w1 = wrl4p[seg][k*4+1];
      float4 w2 = wrl4p[seg][k*4+2], w3 = wrl4p[seg][k*4+3];
      ra0 += l4.x*w0.x + l4.y*w1.x + l4.z*w2.x + l4.w*w3.x;
      ra1 += l4.x*w0.y + l4.y*w1.y + l4.z*w2.y + l4.w*w3.y;
      ra2 += l4.x*w0.z + l4.y*w1.z + l4.z*w2.z + l4.w*w3.z;
      ra3 += l4.x*w0.w + l4.y*w1.w + l4.z*w2.w + l4.w*w3.w;
      float lx=l4.x*ww4.x, ly=l4.y*ww4.y, lz=l4.z*ww4.z, lw=l4.w*ww4.w;
      rc0 += lx*w0.x + ly*w1.x + lz*w2.x + lw*w3.x;
      rc1 += lx*w0.y + ly*w1.y + lz*w2.y + lw*w3.y;
      rc2 += lx*w0.z + ly*w1.z + lz*w2.z + lw*w3.z;
      rc3 += lx*w0.w + ly*w1.w + lz*w2.w + lw*w3.w;
    }
    #pragma unroll
    for (int off=2; off>=1; off>>=1){
      ra0 += __shfl_down(ra0, off, 4); ra1 += __shfl_down(ra1, off, 4);
      ra2 += __shfl_down(ra2, off, 4); ra3 += __shfl_down(ra3, off, 4);
      rc0 += __shfl_down(rc0, off, 4); rc1 += __shfl_down(rc1, off, 4);
      rc2 += __shfl_down(rc2, off, 4); rc3 += __shfl_down(rc3, off, 4);
    }
    if (seg == 0){
      float4 oA; oA.x=ra0; oA.y=ra1; oA.z=ra2; oA.w=ra3;
      float4 oC; oC.x=rc0; oC.y=rc1; oC.z=rc2; oC.w=rc3;
      *reinterpret_cast<float4*>(rowA + ((size_t)b*Nn + row)*Rr) = oA;
      *reinterpret_cast<float4*>(rowC + ((size_t)b*Nn + row)*Rr) = oC;
    }
  }
}

// ---------------- K4: fwd/bwd + read addressing + wr + read vectors --------
__global__ __launch_bounds__(256) void k_readw_rv(
  const float* __restrict__ M, const float* __restrict__ ww_ws,
  const float* __restrict__ er_ws, const float* __restrict__ wv_ws,
  const float* __restrict__ rk_ws, const float* __restrict__ krn_ws,
  const float* __restrict__ rstr_ws, const float* __restrict__ rm_ws,
  const float* __restrict__ P_ws, const float* __restrict__ Q_ws,
  const float* __restrict__ rowA, const float* __restrict__ rowC,
  const float* __restrict__ colAp, const float* __restrict__ colCp,
  const float* __restrict__ diag, const float* __restrict__ wrp,
  const float* __restrict__ prec, float* __restrict__ rv_ws)
{
  const int b = blockIdx.x, t = threadIdx.x;
  __shared__ float rkl[Ww*Rr];
  __shared__ float erl[Ww], wvl[Ww];
  __shared__ __align__(16) float4 red4[Nn];
  __shared__ float wrl[Nn][4];
  __shared__ float wwl[Nn];
  rkl[t] = rk_ws[b*Ww*Rr + t];
  if (t < Ww){ erl[t] = er_ws[b*Ww+t]; wvl[t] = wv_ws[b*Ww+t]; }
  const float ww = ww_ws[b*Nn+t];
  wwl[t] = ww;
  __syncthreads();
  const float pr = prec[b*Nn+t];
  const float dg = diag[b*Nn+t];
  float4 wr4 = *reinterpret_cast<const float4*>(wrp + ((size_t)b*Nn+t)*Rr);
  const float Lnn = (1.0f - 2.0f*ww)*dg + ww*pr;
  float4 rA = *reinterpret_cast<const float4*>(rowA + ((size_t)b*Nn+t)*Rr);
  float4 rC = *reinterpret_cast<const float4*>(rowC + ((size_t)b*Nn+t)*Rr);
  float4 cA = {0,0,0,0}, cC = {0,0,0,0};
  #pragma unroll
  for (int sp=0; sp<4; ++sp){
    cA = f4add(cA, *reinterpret_cast<const float4*>(colAp + (((size_t)sp*Bsz + b)*Nn + t)*Rr));
    cC = f4add(cC, *reinterpret_cast<const float4*>(colCp + (((size_t)sp*Bsz + b)*Nn + t)*Rr));
  }
  float4 Pv = *reinterpret_cast<const float4*>(P_ws + b*Rr);
  float4 Qv = *reinterpret_cast<const float4*>(Q_ws + b*Rr);
  float fwdv[4], bwdv[4];
  fwdv[0] = (1.0f-ww)*rA.x - rC.x + ww*Pv.x - Lnn*wr4.x;
  fwdv[1] = (1.0f-ww)*rA.y - rC.y + ww*Pv.y - Lnn*wr4.y;
  fwdv[2] = (1.0f-ww)*rA.z - rC.z + ww*Pv.z - Lnn*wr4.z;
  fwdv[3] = (1.0f-ww)*rA.w - rC.w + ww*Pv.w - Lnn*wr4.w;
  bwdv[0] = (1.0f-ww)*cA.x - cC.x + pr*Qv.x - Lnn*wr4.x;
  bwdv[1] = (1.0f-ww)*cA.y - cC.y + pr*Qv.y - Lnn*wr4.y;
  bwdv[2] = (1.0f-ww)*cA.z - cC.z + pr*Qv.z - Lnn*wr4.z;
  bwdv[3] = (1.0f-ww)*cA.w - cC.w + pr*Qv.w - Lnn*wr4.w;
  const float* Mrow = M + ((size_t)b*Nn + t)*Ww;
  float s0=0,s1=0,s2=0,s3=0, nrm=0;
  #pragma unroll 4
  for (int w=0;w<Ww;w+=4){
    float4 m4 = *reinterpret_cast<const float4*>(Mrow + w);
    float mvs[4] = {m4.x, m4.y, m4.z, m4.w};
    #pragma unroll
    for (int i=0;i<4;++i){
      int w_ = w+i;
      float mn = mvs[i]*(1.0f - ww*erl[w_]) + ww*wvl[w_];
      nrm += mn*mn;
      float4 k4 = *reinterpret_cast<const float4*>(&rkl[w_*4]);
      s0 += mn*k4.x; s1 += mn*k4.y; s2 += mn*k4.z; s3 += mn*k4.w;
    }
  }
  float mnorm = sqrtf(nrm);
  float4 kn = *reinterpret_cast<const float4*>(krn_ws + b*Rr);
  float4 rs = *reinterpret_cast<const float4*>(rstr_ws + b*Rr);
  float4 aa4;
  aa4.x = rs.x*(s0/(mnorm*kn.x + 1e-6f));
  aa4.y = rs.y*(s1/(mnorm*kn.y + 1e-6f));
  aa4.z = rs.z*(s2/(mnorm*kn.z + 1e-6f));
  aa4.w = rs.w*(s3/(mnorm*kn.w + 1e-6f));
  red4[t] = aa4; __syncthreads();
  for (int st=128; st>0; st>>=1){ if (t<st) red4[t] = f4max(red4[t], red4[t+st]); __syncthreads(); }
  float4 mx4 = red4[0]; __syncthreads();
  float4 e4;
  e4.x = expf(aa4.x - mx4.x); e4.y = expf(aa4.y - mx4.y);
  e4.z = expf(aa4.z - mx4.z); e4.w = expf(aa4.w - mx4.w);
  red4[t] = e4; __syncthreads();
  for (int st=128; st>0; st>>=1){ if (t<st) red4[t] = f4add(red4[t], red4[t+st]); __syncthreads(); }
  float4 sm4 = red4[0];
  float cr[4] = {e4.x/sm4.x, e4.y/sm4.y, e4.z/sm4.z, e4.w/sm4.w};
  float wro[4];
  #pragma unroll
  for (int r=0;r<4;++r){
    float m0 = rm_ws[b*12 + r];
    float m1 = rm_ws[b*12 + 4 + r];
    float m2 = rm_ws[b*12 + 8 + r];
    wro[r] = m0*bwdv[r] + m1*cr[r] + m2*fwdv[r];
  }
  wrl[t][0]=wro[0]; wrl[t][1]=wro[1]; wrl[t][2]=wro[2]; wrl[t][3]=wro[3];
  __syncthreads();
  {
    const int w = t & 63, r = t >> 6;
    const float er_w = erl[w], wv_w = wvl[w];
    float a0=0.0f, a1=0.0f, a2=0.0f, a3=0.0f;
    for (int n=0;n<Nn;n+=4){
      float m0v = M[((size_t)b*Nn + n  )*Ww + w];
      float m1v = M[((size_t)b*Nn + n+1)*Ww + w];
      float m2v = M[((size_t)b*Nn + n+2)*Ww + w];
      float m3v = M[((size_t)b*Nn + n+3)*Ww + w];
      float w0 = wwl[n], w1 = wwl[n+1], w2 = wwl[n+2], w3 = wwl[n+3];
      a0 += (m0v*(1.0f - w0*er_w) + w0*wv_w)*wrl[n  ][r];
      a1 += (m1v*(1.0f - w1*er_w) + w1*wv_w)*wrl[n+1][r];
      a2 += (m2v*(1.0f - w2*er_w) + w2*wv_w)*wrl[n+2][r];
      a3 += (m3v*(1.0f - w3*er_w) + w3*wv_w)*wrl[n+3][r];
    }
    rv_ws[(size_t)b*(Ww*Rr) + w*Rr + r] = (a0+a1)+(a2+a3);
  }
}

// ---------------- K5: output GEMM ------------------------------------------
__global__ __launch_bounds__(256) void k_final(
  const float* __restrict__ h_ws, const float* __restrict__ rv_ws,
  const float* __restrict__ Wo, const float* __restrict__ bo,
  float* __restrict__ out)
{
  const int t = threadIdx.x;
  const int tx = t & 15, ty = t >> 4;
  const int b0 = blockIdx.x*16;
  const int col = blockIdx.y*64 + tx*4;
  __shared__ float Cs[16][68];
  float4 acc = {0,0,0,0};
  for (int kc = 0; kc < 512; kc += 64){
    {
      int rr = t >> 4, cc = (t & 15)*4;
      const float* src = (kc < Uu)
        ? (h_ws  + (size_t)(b0+rr)*Uu + kc + cc)
        : (rv_ws + (size_t)(b0+rr)*(Ww*Rr) + (kc-Uu) + cc);
      *reinterpret_cast<float4*>(&Cs[rr][cc]) = *reinterpret_cast<const float4*>(src);
    }
    __syncthreads();
    const float* Wp = Wo + (size_t)kc*OUTsz + col;
    #pragma unroll 8
    for (int kk=0; kk<64; ++kk){
      float4 w4 = *reinterpret_cast<const float4*>(Wp + (size_t)kk*OUTsz);
      acc = f4fma(Cs[ty][kk], w4, acc);
    }
    __syncthreads();
  }
  float4 b4 = *reinterpret_cast<const float4*>(bo + col);
  acc.x = fminf(fmaxf(acc.x + b4.x, -20.0f), 20.0f);
  acc.y = fminf(fmaxf(acc.y + b4.y, -20.0f), 20.0f);
  acc.z = fminf(fmaxf(acc.z + b4.z, -20.0f), 20.0f);
  acc.w = fminf(fmaxf(acc.w + b4.w, -20.0f), 20.0f);
  *reinterpret_cast<float4*>(out + (size_t)(b0+ty)*OUTsz + col) = acc;
}

extern "C" void kernel_launch(void* const* d_in, const int* in_sizes, int n_in,
                              void* d_out, int out_size, void* d_ws, size_t ws_size,
                              hipStream_t stream)
{
  const float* inputs = (const float*)d_in[0];
  const float* M      = (const float*)d_in[1];
  const float* usage  = (const float*)d_in[2];
  const float* link   = (const float*)d_in[3];
  const float* prec   = (const float*)d_in[4];
  const float* wwp    = (const float*)d_in[5];
  const float* wrp    = (const float*)d_in[6];
  const float* hp     = (const float*)d_in[7];
  const float* cp     = (const float*)d_in[8];
  const float* rvp    = (const float*)d_in[9];
  const float* Wk     = (const float*)d_in[10];
  const float* Wr     = (const float*)d_in[11];
  const float* bl     = (const float*)d_in[12];
  const float* Wi     = (const float*)d_in[13];
  const float* bi     = (const float*)d_in[14];
  const float* Wo     = (const float*)d_in[15];
  const float* bo     = (const float*)d_in[16];

  float* ws = (float*)d_ws;
  float* Wip     = ws;                                  // 256*512
  float* v_ws    = Wip    + (size_t)Uu*512;             // 512*512
  float* h_ws    = v_ws   + (size_t)Bsz*512;            // 512*256
  float* ww_ws   = h_ws   + (size_t)Bsz*Uu;
  float* er_ws   = ww_ws  + (size_t)Bsz*Nn;
  float* wv_ws   = er_ws  + (size_t)Bsz*Ww;
  float* rk_ws   = wv_ws  + (size_t)Bsz*Ww;
  float* krn_ws  = rk_ws  + (size_t)Bsz*Ww*Rr;
  float* rstr_ws = krn_ws + (size_t)Bsz*Rr;
  float* rm_ws   = rstr_ws+ (size_t)Bsz*Rr;
  float* P_ws    = rm_ws  + (size_t)Bsz*3*Rr;
  float* Q_ws    = P_ws   + (size_t)Bsz*Rr;
  float* rowA    = Q_ws   + (size_t)Bsz*Rr;
  float* rowC    = rowA   + (size_t)Bsz*Nn*Rr;
  float* colAp   = rowC   + (size_t)Bsz*Nn*Rr;          // 4 * B*N*R
  float* colCp   = colAp  + (size_t)4*Bsz*Nn*Rr;        // 4 * B*N*R
  float* diag    = colCp  + (size_t)4*Bsz*Nn*Rr;
  float* rv_ws   = diag   + (size_t)Bsz*Nn;

  k_packWi<<<dim3(Uu), dim3(256), 0, stream>>>(Wi, Wip);
  k_lstm<<<dim3(32,8), dim3(512), 0, stream>>>(inputs, rvp, hp, Wk, Wr, bl, cp, h_ws);
  k_ifgemm<<<dim3(32,8), dim3(256), 0, stream>>>(h_ws, Wip, v_ws);
  k_iface2<<<dim3(Bsz), dim3(256), 0, stream>>>(v_ws, bi, usage, wwp, wrp, prec, M,
      ww_ws, er_ws, wv_ws, rk_ws, krn_ws, rstr_ws, rm_ws, P_ws, Q_ws);
  k_link<<<dim3(Bsz,4), dim3(256), 0, stream>>>(link, wrp, ww_ws, rowA, rowC, colAp, colCp, diag);
  k_readw_rv<<<dim3(Bsz), dim3(256), 0, stream>>>(M, ww_ws, er_ws, wv_ws, rk_ws, krn_ws,
      rstr_ws, rm_ws, P_ws, Q_ws, rowA, rowC, colAp, colCp, diag, wrp, prec, rv_ws);
  k_final<<<dim3(32,2), dim3(256), 0, stream>>>(h_ws, rv_ws, Wo, bo, (float*)d_out);
}

// Round 8
// 177.788 us; speedup vs baseline: 1.0627x; 1.0627x over previous
//
#include <hip/hip_runtime.h>
#include <math.h>

#define Bsz 512
#define INsz 128
#define Nn 256
#define Ww 64
#define Rr 4
#define Uu 256
#define OUTsz 128
#define IFACEsz 471
#define XDIM 384   /* IN + W*R */
#define KL 640     /* XDIM + U */
#define G4 1024    /* 4*U */

__device__ __forceinline__ float sigf(float x){ return 1.0f/(1.0f+expf(-x)); }
__device__ __forceinline__ float softplusf_(float x){ return fmaxf(x,0.0f) + log1pf(expf(-fabsf(x))); }
__device__ __forceinline__ float4 f4fma(float s, float4 a, float4 acc){
  acc.x += s*a.x; acc.y += s*a.y; acc.z += s*a.z; acc.w += s*a.w; return acc;
}
__device__ __forceinline__ float4 f4add(float4 a, float4 b){
  a.x+=b.x; a.y+=b.y; a.z+=b.z; a.w+=b.w; return a;
}
__device__ __forceinline__ float4 f4max(float4 a, float4 b){
  a.x=fmaxf(a.x,b.x); a.y=fmaxf(a.y,b.y); a.z=fmaxf(a.z,b.z); a.w=fmaxf(a.w,b.w); return a;
}
__device__ __forceinline__ float4 L4(const float* p){ return *reinterpret_cast<const float4*>(p); }

// ---------------- K0: pad Wi to 512 cols -----------------------------------
__global__ __launch_bounds__(256) void k_packWi(
  const float* __restrict__ Wi, float* __restrict__ Wip)
{
  const int k = blockIdx.x, t = threadIdx.x;
  const int j2 = t + 256;
  Wip[(size_t)k*512 + t]  = Wi[(size_t)k*IFACEsz + t];
  Wip[(size_t)k*512 + j2] = (j2 < IFACEsz) ? Wi[(size_t)k*IFACEsz + j2] : 0.0f;
}

// ---------------- K1: LSTM GEMM + epilogue fused (inline X concat) ---------
__global__ __launch_bounds__(512) void k_lstm(
  const float* __restrict__ inputs, const float* __restrict__ rvp,
  const float* __restrict__ hp, const float* __restrict__ Wk,
  const float* __restrict__ Wr, const float* __restrict__ bl,
  const float* __restrict__ cprev, float* __restrict__ h_out)
{
  const int t = threadIdx.x;
  const int tx = t & 7;
  const int tg = (t >> 3) & 3;
  const int tb = t >> 5;
  const int b0 = blockIdx.x * 16;
  const int cg = blockIdx.y * 32;
  const int col = tg*256 + cg + tx*4;
  __shared__ float Xs[16][68];
  __shared__ float zs[16][4][36];
  float4 acc = {0,0,0,0};
  for (int kc = 0; kc < KL; kc += 64){
    if (t < 256){
      const int rr = t >> 4, cc = (t & 15)*4;
      const int c = kc + cc;
      const float* src;
      if (c < INsz)      src = inputs + (size_t)(b0+rr)*INsz + c;
      else if (c < XDIM) src = rvp + (size_t)(b0+rr)*(Ww*Rr) + (c - INsz);
      else               src = hp + (size_t)(b0+rr)*Uu + (c - XDIM);
      *reinterpret_cast<float4*>(&Xs[rr][cc]) = *reinterpret_cast<const float4*>(src);
    }
    __syncthreads();
    const float* Wp = ((kc < XDIM) ? (Wk + (size_t)kc*G4) : (Wr + (size_t)(kc-XDIM)*G4)) + col;
    #pragma unroll 8
    for (int kk=0; kk<64; ++kk){
      float4 w4 = *reinterpret_cast<const float4*>(Wp + (size_t)kk*G4);
      acc = f4fma(Xs[tb][kk], w4, acc);
    }
    __syncthreads();
  }
  {
    float4 b4 = *reinterpret_cast<const float4*>(bl + col);
    acc = f4add(acc, b4);
  }
  *reinterpret_cast<float4*>(&zs[tb][tg][tx*4]) = acc;
  __syncthreads();
  {
    const int b = t >> 5, c = t & 31;
    float zi = zs[b][0][c], zf = zs[b][1][c], zc_ = zs[b][2][c], zo = zs[b][3][c];
    float cc = sigf(zf)*cprev[(size_t)(b0+b)*Uu + cg + c] + sigf(zi)*tanhf(zc_);
    float h = sigf(zo)*tanhf(cc);
    h = fminf(fmaxf(h,-20.0f),20.0f);
    h_out[(size_t)(b0+b)*Uu + cg + c] = h;
  }
}

// ---------------- K2a: interface GEMM v = h * Wip --------------------------
__global__ __launch_bounds__(256) void k_ifgemm(
  const float* __restrict__ h_ws, const float* __restrict__ Wip, float* __restrict__ v_ws)
{
  const int t = threadIdx.x;
  const int tx = t & 15, ty = t >> 4;
  const int b0 = blockIdx.x*16;
  const int col = blockIdx.y*64 + tx*4;
  __shared__ float Hs[16][68];
  float4 acc = {0,0,0,0};
  for (int kc = 0; kc < Uu; kc += 64){
    {
      int rr = t >> 4, cc = (t & 15)*4;
      *reinterpret_cast<float4*>(&Hs[rr][cc]) =
        *reinterpret_cast<const float4*>(h_ws + (size_t)(b0+rr)*Uu + kc + cc);
    }
    __syncthreads();
    const float* Wp = Wip + (size_t)kc*512 + col;
    #pragma unroll 8
    for (int kk=0; kk<64; ++kk){
      float4 w4 = *reinterpret_cast<const float4*>(Wp + (size_t)kk*512);
      acc = f4fma(Hs[ty][kk], w4, acc);
    }
    __syncthreads();
  }
  *reinterpret_cast<float4*>(v_ws + (size_t)(b0+ty)*512 + col) = acc;
}

// ---------------- K2b: interface logic -------------------------------------
__global__ __launch_bounds__(256) void k_iface2(
  const float* __restrict__ v_ws, const float* __restrict__ bi,
  const float* __restrict__ usage, const float* __restrict__ wwp,
  const float* __restrict__ wrp, const float* __restrict__ prec,
  const float* __restrict__ M,
  float* __restrict__ ww_ws, float* __restrict__ er_ws, float* __restrict__ wv_ws,
  float* __restrict__ rk_ws, float* __restrict__ krn_ws, float* __restrict__ rstr_ws,
  float* __restrict__ rm_ws, float* __restrict__ P_ws, float* __restrict__ Q_ws)
{
  const int b = blockIdx.x, t = threadIdx.x;
  __shared__ float vl[IFACEsz];
  __shared__ float wkey[Ww];
  __shared__ float ul[Nn], sul[Nn], cpl[Nn], red[Nn];
  __shared__ __align__(16) float4 red4[Nn];
  __shared__ float scal[8];
  for (int j=t; j<IFACEsz; j+=256) vl[j] = v_ws[(size_t)b*512 + j] + bi[j];
  __syncthreads();
  if (t < Ww){
    wkey[t] = vl[260+t];
    er_ws[b*Ww+t] = sigf(vl[325+t]);
    wv_ws[b*Ww+t] = vl[389+t];
  }
  rk_ws[b*Ww*Rr + t] = vl[t];
  if (t < Rr){
    rstr_ws[b*Rr+t] = 1.0f + softplusf_(vl[256+t]);
    float ssum = 0.0f;
    for (int w=0;w<Ww;++w){ float v = vl[w*Rr+t]; ssum += v*v; }
    krn_ws[b*Rr+t] = sqrtf(ssum);
    float q0=vl[459+t], q1=vl[463+t], q2=vl[467+t];
    float mm = fmaxf(q0, fmaxf(q1,q2));
    float e0=expf(q0-mm), e1=expf(q1-mm), e2=expf(q2-mm);
    float inv = 1.0f/(e0+e1+e2);
    rm_ws[b*12 + t]     = e0*inv;
    rm_ws[b*12 + 4 + t] = e1*inv;
    rm_ws[b*12 + 8 + t] = e2*inv;
    scal[4+t] = sigf(vl[453+t]);
  }
  if (t == 0){
    scal[0] = 1.0f + softplusf_(vl[324]);
    scal[1] = sigf(vl[457]);
    scal[2] = sigf(vl[458]);
    float ssum=0.0f;
    for (int w=0;w<Ww;++w){ float v=vl[260+w]; ssum += v*v; }
    scal[3] = sqrtf(ssum);
  }
  __syncthreads();
  float4 wr4 = *reinterpret_cast<const float4*>(wrp + ((size_t)b*Nn + t)*Rr);
  float psi = (1.0f - scal[4]*wr4.x)*(1.0f - scal[5]*wr4.y)
            * (1.0f - scal[6]*wr4.z)*(1.0f - scal[7]*wr4.w);
  float us = usage[b*Nn+t], wp = wwp[b*Nn+t];
  float u = (us + wp - us*wp)*psi;
  ul[t] = u;
  __syncthreads();
  int rank = 0;
  for (int m=0;m<Nn;++m){
    float um = ul[m];
    rank += (um < u || (um == u && m < t)) ? 1 : 0;
  }
  sul[rank] = u;
  __syncthreads();
  cpl[t] = sul[t];
  __syncthreads();
  for (int d=1; d<Nn; d<<=1){
    float a = cpl[t];
    float m_ = (t >= d) ? cpl[t-d] : 1.0f;
    __syncthreads();
    cpl[t] = a*m_;
    __syncthreads();
  }
  float cpexcl = (rank == 0) ? 1.0f : cpl[rank-1];
  float alloc = (1.0f - u)*cpexcl;
  const float* Mrow = M + ((size_t)b*Nn + t)*Ww;
  float dot=0.0f, nrm=0.0f;
  #pragma unroll 4
  for (int w=0;w<Ww;w+=4){
    float4 m4 = *reinterpret_cast<const float4*>(Mrow + w);
    dot += m4.x*wkey[w] + m4.y*wkey[w+1] + m4.z*wkey[w+2] + m4.w*wkey[w+3];
    nrm += m4.x*m4.x + m4.y*m4.y + m4.z*m4.z + m4.w*m4.w;
  }
  float sim = dot/(sqrtf(nrm)*scal[3] + 1e-6f);
  float sc = scal[0]*sim;
  red[t] = sc; __syncthreads();
  for (int st=128; st>0; st>>=1){ if (t<st) red[t] = fmaxf(red[t], red[t+st]); __syncthreads(); }
  float mx = red[0]; __syncthreads();
  float e = expf(sc - mx);
  red[t] = e; __syncthreads();
  for (int st=128; st>0; st>>=1){ if (t<st) red[t] += red[t+st]; __syncthreads(); }
  float cw = e/red[0];
  float ww = scal[2]*(scal[1]*alloc + (1.0f - scal[1])*cw);
  ww_ws[b*Nn+t] = ww;
  __syncthreads();
  float pr = prec[b*Nn+t];
  float4 pv; pv.x = pr*wr4.x; pv.y = pr*wr4.y; pv.z = pr*wr4.z; pv.w = pr*wr4.w;
  red4[t] = pv; __syncthreads();
  for (int st=128; st>0; st>>=1){ if (t<st) red4[t] = f4add(red4[t], red4[t+st]); __syncthreads(); }
  if (t==0) *reinterpret_cast<float4*>(P_ws + b*Rr) = red4[0];
  __syncthreads();
  float4 qv; qv.x = ww*wr4.x; qv.y = ww*wr4.y; qv.z = ww*wr4.z; qv.w = ww*wr4.w;
  red4[t] = qv; __syncthreads();
  for (int st=128; st>0; st>>=1){ if (t<st) red4[t] = f4add(red4[t], red4[t+st]); __syncthreads(); }
  if (t==0) *reinterpret_cast<float4*>(Q_ws + b*Rr) = red4[0];
}

// ---------------- K3: link products v5 (4-deep load batching) --------------
// grid (B, 4): strip of 64 rows.
// Phase A: col partials, float4 loads batched 4-deep for MLP; LDS reduce.
// Phase B: row products re-reading the L2-hot strip, 4-deep batching,
//          seg-padded LDS mirrors (conflict-free broadcast).
__global__ __launch_bounds__(256) void k_link(
  const float* __restrict__ link, const float* __restrict__ wrp,
  const float* __restrict__ ww_ws,
  float* __restrict__ rowA, float* __restrict__ rowC,
  float* __restrict__ colAp, float* __restrict__ colCp, float* __restrict__ diag)
{
  const int b = blockIdx.x, s = blockIdx.y, t = threadIdx.x;
  const int n0 = s*64;
  __shared__ __align__(16) float4 wrl4[Nn];      // AoS by n (phase A broadcast)
  __shared__ __align__(16) float4 wrl4p[4][66];  // seg-padded (phase B)
  __shared__ float wws[Nn];
  __shared__ float wwsp[4][68];
  __shared__ __align__(16) float4 cred[4][Nn];   // 16KB reduce buffer
  {
    float4 w4 = *reinterpret_cast<const float4*>(wrp + ((size_t)b*Nn + t)*Rr);
    wrl4[t] = w4;
    wrl4p[t>>6][t&63] = w4;
    float w = ww_ws[(size_t)b*Nn + t];
    wws[t] = w;
    wwsp[t>>6][t&63] = w;
  }
  __syncthreads();
  const float* Lb = link + (size_t)b*Nn*Nn;
  const int cq = t & 63, g = t >> 6;
  const int c4 = cq*4;
  // ---- Phase A: col partials, rows n0+g*16 .. +15, 4-deep load pipeline
  {
    const float* pa = Lb + (size_t)(n0 + g*16)*Nn + c4;
    float4 z = {0,0,0,0};
    float4 a0=z,a1=z,a2=z,a3=z, q0=z,q1=z,q2=z,q3=z;
    float4 b0 = L4(pa), b1 = L4(pa+Nn), b2 = L4(pa+2*Nn), b3 = L4(pa+3*Nn);
    #pragma unroll
    for (int i=0;i<16;i+=4){
      float4 nb0,nb1,nb2,nb3;
      if (i < 12){
        const float* pn = pa + (size_t)(i+4)*Nn;
        nb0 = L4(pn); nb1 = L4(pn+Nn); nb2 = L4(pn+2*Nn); nb3 = L4(pn+3*Nn);
      }
      const int n = n0 + g*16 + i;
      float4 wn; float wwn;
      wn = wrl4[n];   wwn = wws[n];
      a0=f4fma(b0.x,wn,a0); a1=f4fma(b0.y,wn,a1); a2=f4fma(b0.z,wn,a2); a3=f4fma(b0.w,wn,a3);
      q0=f4fma(b0.x*wwn,wn,q0); q1=f4fma(b0.y*wwn,wn,q1); q2=f4fma(b0.z*wwn,wn,q2); q3=f4fma(b0.w*wwn,wn,q3);
      wn = wrl4[n+1]; wwn = wws[n+1];
      a0=f4fma(b1.x,wn,a0); a1=f4fma(b1.y,wn,a1); a2=f4fma(b1.z,wn,a2); a3=f4fma(b1.w,wn,a3);
      q0=f4fma(b1.x*wwn,wn,q0); q1=f4fma(b1.y*wwn,wn,q1); q2=f4fma(b1.z*wwn,wn,q2); q3=f4fma(b1.w*wwn,wn,q3);
      wn = wrl4[n+2]; wwn = wws[n+2];
      a0=f4fma(b2.x,wn,a0); a1=f4fma(b2.y,wn,a1); a2=f4fma(b2.z,wn,a2); a3=f4fma(b2.w,wn,a3);
      q0=f4fma(b2.x*wwn,wn,q0); q1=f4fma(b2.y*wwn,wn,q1); q2=f4fma(b2.z*wwn,wn,q2); q3=f4fma(b2.w*wwn,wn,q3);
      wn = wrl4[n+3]; wwn = wws[n+3];
      a0=f4fma(b3.x,wn,a0); a1=f4fma(b3.y,wn,a1); a2=f4fma(b3.z,wn,a2); a3=f4fma(b3.w,wn,a3);
      q0=f4fma(b3.x*wwn,wn,q0); q1=f4fma(b3.y*wwn,wn,q1); q2=f4fma(b3.z*wwn,wn,q2); q3=f4fma(b3.w*wwn,wn,q3);
      b0=nb0; b1=nb1; b2=nb2; b3=nb3;
    }
    cred[g][c4+0]=a0; cred[g][c4+1]=a1; cred[g][c4+2]=a2; cred[g][c4+3]=a3;
    __syncthreads();
    {
      float4 sA = f4add(f4add(cred[0][t],cred[1][t]),f4add(cred[2][t],cred[3][t]));
      *reinterpret_cast<float4*>(colAp + (((size_t)s*Bsz + b)*Nn + t)*Rr) = sA;
    }
    __syncthreads();
    cred[g][c4+0]=q0; cred[g][c4+1]=q1; cred[g][c4+2]=q2; cred[g][c4+3]=q3;
    __syncthreads();
    {
      float4 sC = f4add(f4add(cred[0][t],cred[1][t]),f4add(cred[2][t],cred[3][t]));
      *reinterpret_cast<float4*>(colCp + (((size_t)s*Bsz + b)*Nn + t)*Rr) = sC;
    }
  }
  // diag for this strip (L2-hot)
  if (t < 64){
    const int n = n0 + t;
    diag[(size_t)b*Nn + n] = Lb[(size_t)n*Nn + n];
  }
  // ---- Phase B: row products; 4 threads/row, 4-deep load pipeline
  {
    const int row = n0 + (t >> 2), seg = t & 3;
    const float* Lr = Lb + (size_t)row*Nn + seg*64;
    float ra0=0,ra1=0,ra2=0,ra3=0, rc0=0,rc1=0,rc2=0,rc3=0;
    float4 c0 = L4(Lr), c1 = L4(Lr+4), c2 = L4(Lr+8), c3 = L4(Lr+12);
    #pragma unroll
    for (int k=0;k<16;k+=4){
      float4 nb0,nb1,nb2,nb3;
      if (k < 12){
        const float* pn = Lr + (k+4)*4;
        nb0 = L4(pn); nb1 = L4(pn+4); nb2 = L4(pn+8); nb3 = L4(pn+12);
      }
      #pragma unroll
      for (int j=0;j<4;++j){
        float4 l4 = (j==0)?c0:(j==1)?c1:(j==2)?c2:c3;
        const int j0 = (k+j)*4;
        float4 ww4 = *reinterpret_cast<const float4*>(&wwsp[seg][j0]);
        float4 w0 = wrl4p[seg][j0], w1 = wrl4p[seg][j0+1];
        float4 w2 = wrl4p[seg][j0+2], w3 = wrl4p[seg][j0+3];
        ra0 += l4.x*w0.x + l4.y*w1.x + l4.z*w2.x + l4.w*w3.x;
        ra1 += l4.x*w0.y + l4.y*w1.y + l4.z*w2.y + l4.w*w3.y;
        ra2 += l4.x*w0.z + l4.y*w1.z + l4.z*w2.z + l4.w*w3.z;
        ra3 += l4.x*w0.w + l4.y*w1.w + l4.z*w2.w + l4.w*w3.w;
        float lx=l4.x*ww4.x, ly=l4.y*ww4.y, lz=l4.z*ww4.z, lw=l4.w*ww4.w;
        rc0 += lx*w0.x + ly*w1.x + lz*w2.x + lw*w3.x;
        rc1 += lx*w0.y + ly*w1.y + lz*w2.y + lw*w3.y;
        rc2 += lx*w0.z + ly*w1.z + lz*w2.z + lw*w3.z;
        rc3 += lx*w0.w + ly*w1.w + lz*w2.w + lw*w3.w;
      }
      c0=nb0; c1=nb1; c2=nb2; c3=nb3;
    }
    #pragma unroll
    for (int off=2; off>=1; off>>=1){
      ra0 += __shfl_down(ra0, off, 4); ra1 += __shfl_down(ra1, off, 4);
      ra2 += __shfl_down(ra2, off, 4); ra3 += __shfl_down(ra3, off, 4);
      rc0 += __shfl_down(rc0, off, 4); rc1 += __shfl_down(rc1, off, 4);
      rc2 += __shfl_down(rc2, off, 4); rc3 += __shfl_down(rc3, off, 4);
    }
    if (seg == 0){
      float4 oA; oA.x=ra0; oA.y=ra1; oA.z=ra2; oA.w=ra3;
      float4 oC; oC.x=rc0; oC.y=rc1; oC.z=rc2; oC.w=rc3;
      *reinterpret_cast<float4*>(rowA + ((size_t)b*Nn + row)*Rr) = oA;
      *reinterpret_cast<float4*>(rowC + ((size_t)b*Nn + row)*Rr) = oC;
    }
  }
}

// ---------------- K4: fwd/bwd + read addressing + wr + read vectors --------
__global__ __launch_bounds__(256) void k_readw_rv(
  const float* __restrict__ M, const float* __restrict__ ww_ws,
  const float* __restrict__ er_ws, const float* __restrict__ wv_ws,
  const float* __restrict__ rk_ws, const float* __restrict__ krn_ws,
  const float* __restrict__ rstr_ws, const float* __restrict__ rm_ws,
  const float* __restrict__ P_ws, const float* __restrict__ Q_ws,
  const float* __restrict__ rowA, const float* __restrict__ rowC,
  const float* __restrict__ colAp, const float* __restrict__ colCp,
  const float* __restrict__ diag, const float* __restrict__ wrp,
  const float* __restrict__ prec, float* __restrict__ rv_ws)
{
  const int b = blockIdx.x, t = threadIdx.x;
  __shared__ float rkl[Ww*Rr];
  __shared__ float erl[Ww], wvl[Ww];
  __shared__ __align__(16) float4 red4[Nn];
  __shared__ float wrl[Nn][4];
  __shared__ float wwl[Nn];
  rkl[t] = rk_ws[b*Ww*Rr + t];
  if (t < Ww){ erl[t] = er_ws[b*Ww+t]; wvl[t] = wv_ws[b*Ww+t]; }
  const float ww = ww_ws[b*Nn+t];
  wwl[t] = ww;
  __syncthreads();
  const float pr = prec[b*Nn+t];
  const float dg = diag[b*Nn+t];
  float4 wr4 = *reinterpret_cast<const float4*>(wrp + ((size_t)b*Nn+t)*Rr);
  const float Lnn = (1.0f - 2.0f*ww)*dg + ww*pr;
  float4 rA = *reinterpret_cast<const float4*>(rowA + ((size_t)b*Nn+t)*Rr);
  float4 rC = *reinterpret_cast<const float4*>(rowC + ((size_t)b*Nn+t)*Rr);
  float4 cA = {0,0,0,0}, cC = {0,0,0,0};
  #pragma unroll
  for (int sp=0; sp<4; ++sp){
    cA = f4add(cA, *reinterpret_cast<const float4*>(colAp + (((size_t)sp*Bsz + b)*Nn + t)*Rr));
    cC = f4add(cC, *reinterpret_cast<const float4*>(colCp + (((size_t)sp*Bsz + b)*Nn + t)*Rr));
  }
  float4 Pv = *reinterpret_cast<const float4*>(P_ws + b*Rr);
  float4 Qv = *reinterpret_cast<const float4*>(Q_ws + b*Rr);
  float fwdv[4], bwdv[4];
  fwdv[0] = (1.0f-ww)*rA.x - rC.x + ww*Pv.x - Lnn*wr4.x;
  fwdv[1] = (1.0f-ww)*rA.y - rC.y + ww*Pv.y - Lnn*wr4.y;
  fwdv[2] = (1.0f-ww)*rA.z - rC.z + ww*Pv.z - Lnn*wr4.z;
  fwdv[3] = (1.0f-ww)*rA.w - rC.w + ww*Pv.w - Lnn*wr4.w;
  bwdv[0] = (1.0f-ww)*cA.x - cC.x + pr*Qv.x - Lnn*wr4.x;
  bwdv[1] = (1.0f-ww)*cA.y - cC.y + pr*Qv.y - Lnn*wr4.y;
  bwdv[2] = (1.0f-ww)*cA.z - cC.z + pr*Qv.z - Lnn*wr4.z;
  bwdv[3] = (1.0f-ww)*cA.w - cC.w + pr*Qv.w - Lnn*wr4.w;
  const float* Mrow = M + ((size_t)b*Nn + t)*Ww;
  float s0=0,s1=0,s2=0,s3=0, nrm=0;
  #pragma unroll 4
  for (int w=0;w<Ww;w+=4){
    float4 m4 = *reinterpret_cast<const float4*>(Mrow + w);
    float mvs[4] = {m4.x, m4.y, m4.z, m4.w};
    #pragma unroll
    for (int i=0;i<4;++i){
      int w_ = w+i;
      float mn = mvs[i]*(1.0f - ww*erl[w_]) + ww*wvl[w_];
      nrm += mn*mn;
      float4 k4 = *reinterpret_cast<const float4*>(&rkl[w_*4]);
      s0 += mn*k4.x; s1 += mn*k4.y; s2 += mn*k4.z; s3 += mn*k4.w;
    }
  }
  float mnorm = sqrtf(nrm);
  float4 kn = *reinterpret_cast<const float4*>(krn_ws + b*Rr);
  float4 rs = *reinterpret_cast<const float4*>(rstr_ws + b*Rr);
  float4 aa4;
  aa4.x = rs.x*(s0/(mnorm*kn.x + 1e-6f));
  aa4.y = rs.y*(s1/(mnorm*kn.y + 1e-6f));
  aa4.z = rs.z*(s2/(mnorm*kn.z + 1e-6f));
  aa4.w = rs.w*(s3/(mnorm*kn.w + 1e-6f));
  red4[t] = aa4; __syncthreads();
  for (int st=128; st>0; st>>=1){ if (t<st) red4[t] = f4max(red4[t], red4[t+st]); __syncthreads(); }
  float4 mx4 = red4[0]; __syncthreads();
  float4 e4;
  e4.x = expf(aa4.x - mx4.x); e4.y = expf(aa4.y - mx4.y);
  e4.z = expf(aa4.z - mx4.z); e4.w = expf(aa4.w - mx4.w);
  red4[t] = e4; __syncthreads();
  for (int st=128; st>0; st>>=1){ if (t<st) red4[t] = f4add(red4[t], red4[t+st]); __syncthreads(); }
  float4 sm4 = red4[0];
  float cr[4] = {e4.x/sm4.x, e4.y/sm4.y, e4.z/sm4.z, e4.w/sm4.w};
  float wro[4];
  #pragma unroll
  for (int r=0;r<4;++r){
    float m0 = rm_ws[b*12 + r];
    float m1 = rm_ws[b*12 + 4 + r];
    float m2 = rm_ws[b*12 + 8 + r];
    wro[r] = m0*bwdv[r] + m1*cr[r] + m2*fwdv[r];
  }
  wrl[t][0]=wro[0]; wrl[t][1]=wro[1]; wrl[t][2]=wro[2]; wrl[t][3]=wro[3];
  __syncthreads();
  {
    const int w = t & 63, r = t >> 6;
    const float er_w = erl[w], wv_w = wvl[w];
    float a0=0.0f, a1=0.0f, a2=0.0f, a3=0.0f;
    for (int n=0;n<Nn;n+=4){
      float m0v = M[((size_t)b*Nn + n  )*Ww + w];
      float m1v = M[((size_t)b*Nn + n+1)*Ww + w];
      float m2v = M[((size_t)b*Nn + n+2)*Ww + w];
      float m3v = M[((size_t)b*Nn + n+3)*Ww + w];
      float w0 = wwl[n], w1 = wwl[n+1], w2 = wwl[n+2], w3 = wwl[n+3];
      a0 += (m0v*(1.0f - w0*er_w) + w0*wv_w)*wrl[n  ][r];
      a1 += (m1v*(1.0f - w1*er_w) + w1*wv_w)*wrl[n+1][r];
      a2 += (m2v*(1.0f - w2*er_w) + w2*wv_w)*wrl[n+2][r];
      a3 += (m3v*(1.0f - w3*er_w) + w3*wv_w)*wrl[n+3][r];
    }
    rv_ws[(size_t)b*(Ww*Rr) + w*Rr + r] = (a0+a1)+(a2+a3);
  }
}

// ---------------- K5: output GEMM ------------------------------------------
__global__ __launch_bounds__(256) void k_final(
  const float* __restrict__ h_ws, const float* __restrict__ rv_ws,
  const float* __restrict__ Wo, const float* __restrict__ bo,
  float* __restrict__ out)
{
  const int t = threadIdx.x;
  const int tx = t & 15, ty = t >> 4;
  const int b0 = blockIdx.x*16;
  const int col = blockIdx.y*64 + tx*4;
  __shared__ float Cs[16][68];
  float4 acc = {0,0,0,0};
  for (int kc = 0; kc < 512; kc += 64){
    {
      int rr = t >> 4, cc = (t & 15)*4;
      const float* src = (kc < Uu)
        ? (h_ws  + (size_t)(b0+rr)*Uu + kc + cc)
        : (rv_ws + (size_t)(b0+rr)*(Ww*Rr) + (kc-Uu) + cc);
      *reinterpret_cast<float4*>(&Cs[rr][cc]) = *reinterpret_cast<const float4*>(src);
    }
    __syncthreads();
    const float* Wp = Wo + (size_t)kc*OUTsz + col;
    #pragma unroll 8
    for (int kk=0; kk<64; ++kk){
      float4 w4 = *reinterpret_cast<const float4*>(Wp + (size_t)kk*OUTsz);
      acc = f4fma(Cs[ty][kk], w4, acc);
    }
    __syncthreads();
  }
  float4 b4 = *reinterpret_cast<const float4*>(bo + col);
  acc.x = fminf(fmaxf(acc.x + b4.x, -20.0f), 20.0f);
  acc.y = fminf(fmaxf(acc.y + b4.y, -20.0f), 20.0f);
  acc.z = fminf(fmaxf(acc.z + b4.z, -20.0f), 20.0f);
  acc.w = fminf(fmaxf(acc.w + b4.w, -20.0f), 20.0f);
  *reinterpret_cast<float4*>(out + (size_t)(b0+ty)*OUTsz + col) = acc;
}

extern "C" void kernel_launch(void* const* d_in, const int* in_sizes, int n_in,
                              void* d_out, int out_size, void* d_ws, size_t ws_size,
                              hipStream_t stream)
{
  const float* inputs = (const float*)d_in[0];
  const float* M      = (const float*)d_in[1];
  const float* usage  = (const float*)d_in[2];
  const float* link   = (const float*)d_in[3];
  const float* prec   = (const float*)d_in[4];
  const float* wwp    = (const float*)d_in[5];
  const float* wrp    = (const float*)d_in[6];
  const float* hp     = (const float*)d_in[7];
  const float* cp     = (const float*)d_in[8];
  const float* rvp    = (const float*)d_in[9];
  const float* Wk     = (const float*)d_in[10];
  const float* Wr     = (const float*)d_in[11];
  const float* bl     = (const float*)d_in[12];
  const float* Wi     = (const float*)d_in[13];
  const float* bi     = (const float*)d_in[14];
  const float* Wo     = (const float*)d_in[15];
  const float* bo     = (const float*)d_in[16];

  float* ws = (float*)d_ws;
  float* Wip     = ws;                                  // 256*512
  float* v_ws    = Wip    + (size_t)Uu*512;             // 512*512
  float* h_ws    = v_ws   + (size_t)Bsz*512;             // 512*256
  float* ww_ws   = h_ws   + (size_t)Bsz*Uu;
  float* er_ws   = ww_ws  + (size_t)Bsz*Nn;
  float* wv_ws   = er_ws  + (size_t)Bsz*Ww;
  float* rk_ws   = wv_ws  + (size_t)Bsz*Ww;
  float* krn_ws  = rk_ws  + (size_t)Bsz*Ww*Rr;
  float* rstr_ws = krn_ws + (size_t)Bsz*Rr;
  float* rm_ws   = rstr_ws+ (size_t)Bsz*Rr;
  float* P_ws    = rm_ws  + (size_t)Bsz*3*Rr;
  float* Q_ws    = P_ws   + (size_t)Bsz*Rr;
  float* rowA    = Q_ws   + (size_t)Bsz*Rr;
  float* rowC    = rowA   + (size_t)Bsz*Nn*Rr;
  float* colAp   = rowC   + (size_t)Bsz*Nn*Rr;          // 4 * B*N*R
  float* colCp   = colAp  + (size_t)4*Bsz*Nn*Rr;        // 4 * B*N*R
  float* diag    = colCp  + (size_t)4*Bsz*Nn*Rr;
  float* rv_ws   = diag   + (size_t)Bsz*Nn;

  k_packWi<<<dim3(Uu), dim3(256), 0, stream>>>(Wi, Wip);
  k_lstm<<<dim3(32,8), dim3(512), 0, stream>>>(inputs, rvp, hp, Wk, Wr, bl, cp, h_ws);
  k_ifgemm<<<dim3(32,8), dim3(256), 0, stream>>>(h_ws, Wip, v_ws);
  k_iface2<<<dim3(Bsz), dim3(256), 0, stream>>>(v_ws, bi, usage, wwp, wrp, prec, M,
      ww_ws, er_ws, wv_ws, rk_ws, krn_ws, rstr_ws, rm_ws, P_ws, Q_ws);
  k_link<<<dim3(Bsz,4), dim3(256), 0, stream>>>(link, wrp, ww_ws, rowA, rowC, colAp, colCp, diag);
  k_readw_rv<<<dim3(Bsz), dim3(256), 0, stream>>>(M, ww_ws, er_ws, wv_ws, rk_ws, krn_ws,
      rstr_ws, rm_ws, P_ws, Q_ws, rowA, rowC, colAp, colCp, diag, wrp, prec, rv_ws);
  k_final<<<dim3(32,2), dim3(256), 0, stream>>>(h_ws, rv_ws, Wo, bo, (float*)d_out);
}